// Round 1
// baseline (2047.742 us; speedup 1.0000x reference)
//
#include <hip/hip_runtime.h>

#define EMB 128

// ---- degree count -------------------------------------------------------
__global__ void k_deg(const int* __restrict__ dst, int* __restrict__ deg, int E) {
    int i = blockIdx.x * blockDim.x + threadIdx.x;
    int stride = gridDim.x * blockDim.x;
    for (; i < E; i += stride) atomicAdd(&deg[dst[i]], 1);
}

// ---- norm = 1/sqrt(max(deg,1)) -----------------------------------------
__global__ void k_norm(const int* __restrict__ deg, float* __restrict__ nrm, int N) {
    int i = blockIdx.x * blockDim.x + threadIdx.x;
    if (i < N) nrm[i] = 1.0f / sqrtf(fmaxf((float)deg[i], 1.0f));
}

// ---- single-block exclusive prefix scan over deg -> offs, pos ----------
__global__ __launch_bounds__(1024) void k_scan(const int* __restrict__ deg,
                                               int* __restrict__ offs,
                                               int* __restrict__ pos, int n) {
    __shared__ int wsum[16];
    __shared__ int carry_s;
    const int t = threadIdx.x;
    const int lane = t & 63;
    const int wid = t >> 6;
    if (t == 0) carry_s = 0;
    __syncthreads();
    for (int base = 0; base < n; base += 1024) {
        const int i = base + t;
        const int v = (i < n) ? deg[i] : 0;
        int s = v;
        #pragma unroll
        for (int o = 1; o < 64; o <<= 1) {
            int u = __shfl_up(s, o);
            if (lane >= o) s += u;
        }
        if (lane == 63) wsum[wid] = s;
        __syncthreads();
        if (t < 16) {
            int ws = wsum[t];
            #pragma unroll
            for (int o = 1; o < 16; o <<= 1) {
                int u = __shfl_up(ws, o);
                if (t >= o) ws += u;
            }
            wsum[t] = ws;
        }
        __syncthreads();
        const int waveoff = (wid > 0) ? wsum[wid - 1] : 0;
        const int carry = carry_s;
        const int excl = carry + waveoff + s - v;
        if (i < n) { offs[i] = excl; pos[i] = excl; }
        const int total = wsum[15];
        __syncthreads();
        if (t == 0) carry_s = carry + total;
        __syncthreads();
    }
    if (t == 0) offs[n] = carry_s;
}

// ---- counting-sort scatter: csr_src grouped by dst ---------------------
__global__ void k_fill(const int* __restrict__ src, const int* __restrict__ dst,
                       int* __restrict__ pos, int* __restrict__ csr, int E) {
    int i = blockIdx.x * blockDim.x + threadIdx.x;
    int stride = gridDim.x * blockDim.x;
    for (; i < E; i += stride) {
        int p = atomicAdd(&pos[dst[i]], 1);
        csr[p] = src[i];
    }
}

// ---- one SGC hop: out[i] = nrm[i] * sum_{e:dst=i} in[src[e]]*nrm[src[e]]
// one wave per node; lane l owns dims [2l, 2l+1]
__global__ __launch_bounds__(256) void k_hop(const float* __restrict__ in,
                                             const float* __restrict__ nrm,
                                             const int* __restrict__ offs,
                                             const int* __restrict__ csr,
                                             float* __restrict__ out, int N) {
    const int lane = threadIdx.x & 63;
    int w = blockIdx.x * (blockDim.x >> 6) + (threadIdx.x >> 6);
    const int nw = gridDim.x * (blockDim.x >> 6);
    for (int i = w; i < N; i += nw) {
        const int jb = offs[i], je = offs[i + 1];
        float ax = 0.f, ay = 0.f;
        int j = jb;
        for (; j + 4 <= je; j += 4) {
            const int c0 = csr[j + 0], c1 = csr[j + 1], c2 = csr[j + 2], c3 = csr[j + 3];
            const float n0 = nrm[c0], n1 = nrm[c1], n2 = nrm[c2], n3 = nrm[c3];
            const float2 v0 = *(const float2*)&in[(size_t)c0 * EMB + 2 * lane];
            const float2 v1 = *(const float2*)&in[(size_t)c1 * EMB + 2 * lane];
            const float2 v2 = *(const float2*)&in[(size_t)c2 * EMB + 2 * lane];
            const float2 v3 = *(const float2*)&in[(size_t)c3 * EMB + 2 * lane];
            ax += v0.x * n0 + v1.x * n1 + v2.x * n2 + v3.x * n3;
            ay += v0.y * n0 + v1.y * n1 + v2.y * n2 + v3.y * n3;
        }
        for (; j < je; ++j) {
            const int c = csr[j];
            const float n0 = nrm[c];
            const float2 v = *(const float2*)&in[(size_t)c * EMB + 2 * lane];
            ax += v.x * n0;
            ay += v.y * n0;
        }
        const float ni = nrm[i];
        float2 o;
        o.x = ax * ni;
        o.y = ay * ni;
        *(float2*)&out[(size_t)i * EMB + 2 * lane] = o;
    }
}

// ---- linear: y = h @ W.T + b -------------------------------------------
// W[j][k] staged in LDS at [k*128 + (j ^ (k&31))] (bank-conflict-free both ways)
__global__ __launch_bounds__(256) void k_linear(const float* __restrict__ h,
                                                const float* __restrict__ W,
                                                const float* __restrict__ bias,
                                                float* __restrict__ y, int N) {
    __shared__ float Wt[EMB * EMB];  // exactly 64 KB
    for (int idx = threadIdx.x; idx < EMB * EMB; idx += blockDim.x) {
        const int j = idx >> 7, k = idx & 127;
        Wt[k * EMB + (j ^ (k & 31))] = W[idx];
    }
    __syncthreads();
    const int lane = threadIdx.x & 63;
    int w = blockIdx.x * (blockDim.x >> 6) + (threadIdx.x >> 6);
    const int nw = gridDim.x * (blockDim.x >> 6);
    const float b0 = bias[lane], b1 = bias[lane + 64];
    const int j0 = lane, j1 = lane + 64;
    for (int i = w; i < N; i += nw) {
        const float2 hv = *(const float2*)&h[(size_t)i * EMB + 2 * lane];
        float a0 = b0, a1 = b1;
        #pragma unroll
        for (int m = 0; m < 64; ++m) {
            const float hx = __shfl(hv.x, m);
            const float hy = __shfl(hv.y, m);
            const int k0 = 2 * m, k1 = 2 * m + 1;
            a0 += hx * Wt[k0 * EMB + (j0 ^ (k0 & 31))] + hy * Wt[k1 * EMB + (j0 ^ (k1 & 31))];
            a1 += hx * Wt[k0 * EMB + (j1 ^ (k0 & 31))] + hy * Wt[k1 * EMB + (j1 ^ (k1 & 31))];
        }
        float2 o;
        o.x = a0;
        o.y = a1;
        *(float2*)&y[(size_t)i * EMB + 2 * lane] = o;
    }
}

// ---- per-edge dots: half-wave (32 lanes x float4) per edge -------------
__global__ __launch_bounds__(256) void k_dot(const float* __restrict__ y,
                                             const int* __restrict__ src,
                                             const int* __restrict__ dst,
                                             const int* __restrict__ nsrc,
                                             const int* __restrict__ ndst,
                                             float* __restrict__ out, int E) {
    const int lane = threadIdx.x & 63;
    const int sub = lane >> 5;  // which edge of the pair
    const int l = lane & 31;
    int w = blockIdx.x * (blockDim.x >> 6) + (threadIdx.x >> 6);
    const int nw = gridDim.x * (blockDim.x >> 6);
    for (int p = w; p < E; p += nw) {  // E pairs cover 2E edges
        const int e = 2 * p + sub;
        int s, d;
        if (e < E) { s = src[e]; d = dst[e]; }
        else       { s = nsrc[e - E]; d = ndst[e - E]; }
        const float4 a = *(const float4*)&y[(size_t)s * EMB + 4 * l];
        const float4 c = *(const float4*)&y[(size_t)d * EMB + 4 * l];
        float v = a.x * c.x + a.y * c.y + a.z * c.z + a.w * c.w;
        v += __shfl_xor(v, 16);
        v += __shfl_xor(v, 8);
        v += __shfl_xor(v, 4);
        v += __shfl_xor(v, 2);
        v += __shfl_xor(v, 1);
        if (l == 0) out[e] = v;
    }
}

extern "C" void kernel_launch(void* const* d_in, const int* in_sizes, int n_in,
                              void* d_out, int out_size, void* d_ws, size_t ws_size,
                              hipStream_t stream) {
    const float* emb = (const float*)d_in[0];
    const float* W   = (const float*)d_in[1];
    const float* b   = (const float*)d_in[2];
    const int* src   = (const int*)d_in[3];
    const int* dst   = (const int*)d_in[4];
    const int* nsrc  = (const int*)d_in[5];
    const int* ndst  = (const int*)d_in[6];
    const int N = in_sizes[0] / EMB;
    const int E = in_sizes[3];
    float* out = (float*)d_out;

    char* wp = (char*)d_ws;
    const size_t szA = (size_t)N * EMB * sizeof(float);
    float* A    = (float*)(wp);                              // H1, then Y
    float* B    = (float*)(wp + szA);                        // H2
    float* nrm  = (float*)(wp + 2 * szA);
    int*   deg  = (int*)(wp + 2 * szA + (size_t)N * 4);
    int*   offs = (int*)(wp + 2 * szA + 2 * (size_t)N * 4);
    int*   pos  = offs + (N + 1);
    int*   csr  = pos + (N + 1);

    hipMemsetAsync(deg, 0, (size_t)N * 4, stream);
    k_deg<<<2048, 256, 0, stream>>>(dst, deg, E);
    k_norm<<<(N + 255) / 256, 256, 0, stream>>>(deg, nrm, N);
    k_scan<<<1, 1024, 0, stream>>>(deg, offs, pos, N);
    k_fill<<<2048, 256, 0, stream>>>(src, dst, pos, csr, E);
    k_hop<<<(N + 3) / 4, 256, 0, stream>>>(emb, nrm, offs, csr, A, N);
    k_hop<<<(N + 3) / 4, 256, 0, stream>>>(A, nrm, offs, csr, B, N);
    k_linear<<<2048, 256, 0, stream>>>(B, W, b, A, N);
    k_dot<<<8192, 256, 0, stream>>>(A, src, dst, nsrc, ndst, out, E);
}

// Round 2
// 1891.912 us; speedup vs baseline: 1.0824x; 1.0824x over previous
//
#include <hip/hip_runtime.h>

#define EMB 128

// ---- degree count (pos dst always; neg dst if degn != null) -------------
__global__ void k_count2(const int* __restrict__ dst, const int* __restrict__ ndst,
                         int* __restrict__ deg, int* __restrict__ degn, int E) {
    int i = blockIdx.x * blockDim.x + threadIdx.x;
    int stride = gridDim.x * blockDim.x;
    for (; i < E; i += stride) {
        atomicAdd(&deg[dst[i]], 1);
        if (degn) atomicAdd(&degn[ndst[i]], 1);
    }
}

// ---- norm = 1/sqrt(max(deg,1)), norm2 = norm*norm ------------------------
__global__ void k_norm(const int* __restrict__ deg, float* __restrict__ nrm,
                       float* __restrict__ nrm2, int N) {
    int i = blockIdx.x * blockDim.x + threadIdx.x;
    if (i < N) {
        float d = fmaxf((float)deg[i], 1.0f);
        float r = 1.0f / sqrtf(d);
        nrm[i] = r;
        nrm2[i] = r * r;
    }
}

// ---- 3-phase scan: phase 1, per-block (256) sums -------------------------
__global__ __launch_bounds__(256) void k_scan1(const int* __restrict__ v,
                                               int* __restrict__ bsum, int n) {
    __shared__ int w4[4];
    const int t = threadIdx.x, lane = t & 63, wid = t >> 6;
    const int i = blockIdx.x * 256 + t;
    int x = (i < n) ? v[i] : 0;
    #pragma unroll
    for (int o = 32; o > 0; o >>= 1) x += __shfl_xor(x, o);
    if (lane == 0) w4[wid] = x;
    __syncthreads();
    if (t == 0) bsum[blockIdx.x] = w4[0] + w4[1] + w4[2] + w4[3];
}

// ---- phase 2: single-block exclusive scan of bsum (in place), total out --
__global__ __launch_bounds__(512) void k_scan2(int* __restrict__ bsum, int B,
                                               int* __restrict__ total_out) {
    __shared__ int w8[8];
    __shared__ int carry_s;
    const int t = threadIdx.x, lane = t & 63, wid = t >> 6;
    if (t == 0) carry_s = 0;
    __syncthreads();
    for (int base = 0; base < B; base += 512) {
        const int idx = base + t;
        const int v = (idx < B) ? bsum[idx] : 0;
        int s = v;
        #pragma unroll
        for (int o = 1; o < 64; o <<= 1) {
            int g = __shfl_up(s, o);
            if (lane >= o) s += g;
        }
        if (lane == 63) w8[wid] = s;
        __syncthreads();
        if (t < 8) {
            int u = w8[t];
            #pragma unroll
            for (int o = 1; o < 8; o <<= 1) {
                int g = __shfl_up(u, o);
                if (t >= o) u += g;
            }
            w8[t] = u;
        }
        __syncthreads();
        const int woff = wid ? w8[wid - 1] : 0;
        const int c = carry_s;
        if (idx < B) bsum[idx] = c + woff + s - v;
        const int tot = w8[7];
        __syncthreads();
        if (t == 0) carry_s = c + tot;
        __syncthreads();
    }
    if (t == 0 && total_out) *total_out = carry_s;
}

// ---- phase 3: per-block rescan with block offset -> offs, pos ------------
__global__ __launch_bounds__(256) void k_scan3(const int* __restrict__ v,
                                               const int* __restrict__ bexcl,
                                               int* __restrict__ offs,
                                               int* __restrict__ pos, int n) {
    __shared__ int w4[4];
    const int t = threadIdx.x, lane = t & 63, wid = t >> 6;
    const int i = blockIdx.x * 256 + t;
    const int x = (i < n) ? v[i] : 0;
    int s = x;
    #pragma unroll
    for (int o = 1; o < 64; o <<= 1) {
        int g = __shfl_up(s, o);
        if (lane >= o) s += g;
    }
    if (lane == 63) w4[wid] = s;
    __syncthreads();
    int woff = 0;
    for (int k = 0; k < wid; ++k) woff += w4[k];
    const int excl = bexcl[blockIdx.x] + woff + s - x;
    if (i < n) { offs[i] = excl; pos[i] = excl; }
}

// ---- counting-sort fill: src (and optionally edge id) grouped by dst -----
__global__ void k_fill2(const int* __restrict__ src, const int* __restrict__ dst,
                        int* __restrict__ pos, int* __restrict__ cs,
                        int* __restrict__ ce, int E) {
    int i = blockIdx.x * blockDim.x + threadIdx.x;
    int stride = gridDim.x * blockDim.x;
    for (; i < E; i += stride) {
        int p = atomicAdd(&pos[dst[i]], 1);
        cs[p] = src[i];
        if (ce) ce[p] = i;
    }
}

// ---- elementwise: o[i][*] = x[i][*] * s[i] --------------------------------
__global__ void k_scale(const float* __restrict__ x, const float* __restrict__ s,
                        float* __restrict__ o, int total4) {
    int idx = blockIdx.x * blockDim.x + threadIdx.x;
    if (idx < total4) {
        const int node = idx >> 5;  // 32 float4 per 128-float row
        float4 v = ((const float4*)x)[idx];
        const float f = s[node];
        float4 r; r.x = v.x * f; r.y = v.y * f; r.z = v.z * f; r.w = v.w * f;
        ((float4*)o)[idx] = r;
    }
}

// ---- one gather-sum hop: out[i] = oscale[i] * sum_{e: dst=i} in[src[e]] ---
// half-wave (32 lanes x float4) per node
__global__ __launch_bounds__(256) void k_hop(const float* __restrict__ in,
                                             const float* __restrict__ oscale,
                                             const int* __restrict__ offs,
                                             const int* __restrict__ csr,
                                             float* __restrict__ out, int N) {
    const int l = threadIdx.x & 31;
    int hw = (blockIdx.x * blockDim.x + threadIdx.x) >> 5;
    const int nhw = (gridDim.x * blockDim.x) >> 5;
    for (int i = hw; i < N; i += nhw) {
        const int jb = offs[i], je = offs[i + 1];
        float4 acc; acc.x = 0.f; acc.y = 0.f; acc.z = 0.f; acc.w = 0.f;
        int j = jb;
        for (; j + 4 <= je; j += 4) {
            const int c0 = csr[j], c1 = csr[j + 1], c2 = csr[j + 2], c3 = csr[j + 3];
            const float4 v0 = *(const float4*)&in[(size_t)c0 * EMB + 4 * l];
            const float4 v1 = *(const float4*)&in[(size_t)c1 * EMB + 4 * l];
            const float4 v2 = *(const float4*)&in[(size_t)c2 * EMB + 4 * l];
            const float4 v3 = *(const float4*)&in[(size_t)c3 * EMB + 4 * l];
            acc.x += v0.x; acc.y += v0.y; acc.z += v0.z; acc.w += v0.w;
            acc.x += v1.x; acc.y += v1.y; acc.z += v1.z; acc.w += v1.w;
            acc.x += v2.x; acc.y += v2.y; acc.z += v2.z; acc.w += v2.w;
            acc.x += v3.x; acc.y += v3.y; acc.z += v3.z; acc.w += v3.w;
        }
        for (; j < je; ++j) {
            const int c = csr[j];
            const float4 v = *(const float4*)&in[(size_t)c * EMB + 4 * l];
            acc.x += v.x; acc.y += v.y; acc.z += v.z; acc.w += v.w;
        }
        const float s = oscale[i];
        float4 o; o.x = acc.x * s; o.y = acc.y * s; o.z = acc.z * s; o.w = acc.w * s;
        *(float4*)&out[(size_t)i * EMB + 4 * l] = o;
    }
}

// ---- linear: y = h @ W.T + bias ------------------------------------------
__global__ __launch_bounds__(256) void k_linear(const float* __restrict__ h,
                                                const float* __restrict__ W,
                                                const float* __restrict__ bias,
                                                float* __restrict__ y, int N) {
    __shared__ float Wt[EMB * EMB];  // 64 KB, XOR-swizzled transpose
    for (int idx = threadIdx.x; idx < EMB * EMB; idx += blockDim.x) {
        const int j = idx >> 7, k = idx & 127;
        Wt[k * EMB + (j ^ (k & 31))] = W[idx];
    }
    __syncthreads();
    const int lane = threadIdx.x & 63;
    int w = blockIdx.x * (blockDim.x >> 6) + (threadIdx.x >> 6);
    const int nw = gridDim.x * (blockDim.x >> 6);
    const float b0 = bias[lane], b1 = bias[lane + 64];
    const int j0 = lane, j1 = lane + 64;
    for (int i = w; i < N; i += nw) {
        const float2 hv = *(const float2*)&h[(size_t)i * EMB + 2 * lane];
        float a0 = b0, a1 = b1;
        #pragma unroll
        for (int m = 0; m < 64; ++m) {
            const float hx = __shfl(hv.x, m);
            const float hy = __shfl(hv.y, m);
            const int k0 = 2 * m, k1 = 2 * m + 1;
            a0 += hx * Wt[k0 * EMB + (j0 ^ (k0 & 31))] + hy * Wt[k1 * EMB + (j0 ^ (k1 & 31))];
            a1 += hx * Wt[k0 * EMB + (j1 ^ (k0 & 31))] + hy * Wt[k1 * EMB + (j1 ^ (k1 & 31))];
        }
        float2 o; o.x = a0; o.y = a1;
        *(float2*)&y[(size_t)i * EMB + 2 * lane] = o;
    }
}

// ---- grouped edge dots: half-wave per node, dst row cached in registers --
__global__ __launch_bounds__(256) void k_dotg(const float* __restrict__ y,
                                              const int* __restrict__ offs,
                                              const int* __restrict__ cs,
                                              const int* __restrict__ ce,
                                              float* __restrict__ out, int N) {
    const int l = threadIdx.x & 31;
    int hw = (blockIdx.x * blockDim.x + threadIdx.x) >> 5;
    const int nhw = (gridDim.x * blockDim.x) >> 5;
    for (int i = hw; i < N; i += nhw) {
        const int jb = offs[i], je = offs[i + 1];
        if (jb == je) continue;
        const float4 d = *(const float4*)&y[(size_t)i * EMB + 4 * l];
        int j = jb;
        for (; j + 2 <= je; j += 2) {
            const int c0 = cs[j], c1 = cs[j + 1];
            const int e0 = ce[j], e1 = ce[j + 1];
            const float4 a0 = *(const float4*)&y[(size_t)c0 * EMB + 4 * l];
            const float4 a1 = *(const float4*)&y[(size_t)c1 * EMB + 4 * l];
            float v0 = a0.x * d.x + a0.y * d.y + a0.z * d.z + a0.w * d.w;
            float v1 = a1.x * d.x + a1.y * d.y + a1.z * d.z + a1.w * d.w;
            v0 += __shfl_xor(v0, 16); v1 += __shfl_xor(v1, 16);
            v0 += __shfl_xor(v0, 8);  v1 += __shfl_xor(v1, 8);
            v0 += __shfl_xor(v0, 4);  v1 += __shfl_xor(v1, 4);
            v0 += __shfl_xor(v0, 2);  v1 += __shfl_xor(v1, 2);
            v0 += __shfl_xor(v0, 1);  v1 += __shfl_xor(v1, 1);
            if (l == 0) { out[e0] = v0; out[e1] = v1; }
        }
        if (j < je) {
            const int c0 = cs[j], e0 = ce[j];
            const float4 a0 = *(const float4*)&y[(size_t)c0 * EMB + 4 * l];
            float v0 = a0.x * d.x + a0.y * d.y + a0.z * d.z + a0.w * d.w;
            v0 += __shfl_xor(v0, 16); v0 += __shfl_xor(v0, 8);
            v0 += __shfl_xor(v0, 4);  v0 += __shfl_xor(v0, 2);
            v0 += __shfl_xor(v0, 1);
            if (l == 0) out[e0] = v0;
        }
    }
}

// ---- fallback ungrouped dots (proven path, used if ws too small) ---------
__global__ __launch_bounds__(256) void k_dot(const float* __restrict__ y,
                                             const int* __restrict__ src,
                                             const int* __restrict__ dst,
                                             const int* __restrict__ nsrc,
                                             const int* __restrict__ ndst,
                                             float* __restrict__ out, int E) {
    const int lane = threadIdx.x & 63;
    const int sub = lane >> 5;
    const int l = lane & 31;
    int w = blockIdx.x * (blockDim.x >> 6) + (threadIdx.x >> 6);
    const int nw = gridDim.x * (blockDim.x >> 6);
    for (int p = w; p < E; p += nw) {
        const int e = 2 * p + sub;
        int s, d;
        if (e < E) { s = src[e]; d = dst[e]; }
        else       { s = nsrc[e - E]; d = ndst[e - E]; }
        const float4 a = *(const float4*)&y[(size_t)s * EMB + 4 * l];
        const float4 c = *(const float4*)&y[(size_t)d * EMB + 4 * l];
        float v = a.x * c.x + a.y * c.y + a.z * c.z + a.w * c.w;
        v += __shfl_xor(v, 16); v += __shfl_xor(v, 8); v += __shfl_xor(v, 4);
        v += __shfl_xor(v, 2);  v += __shfl_xor(v, 1);
        if (l == 0) out[e] = v;
    }
}

extern "C" void kernel_launch(void* const* d_in, const int* in_sizes, int n_in,
                              void* d_out, int out_size, void* d_ws, size_t ws_size,
                              hipStream_t stream) {
    const float* emb = (const float*)d_in[0];
    const float* W   = (const float*)d_in[1];
    const float* bia = (const float*)d_in[2];
    const int* src   = (const int*)d_in[3];
    const int* dst   = (const int*)d_in[4];
    const int* nsrc  = (const int*)d_in[5];
    const int* ndst  = (const int*)d_in[6];
    const int N = in_sizes[0] / EMB;
    const int E = in_sizes[3];
    float* out = (float*)d_out;

    const size_t szA = (size_t)N * EMB * sizeof(float);
    const size_t szN = (size_t)N * sizeof(int);
    const size_t szE = (size_t)E * sizeof(int);
    const int SCAN_B = (N + 255) / 256;

    // grouped path needs: 2*szA + 4*szE + 8*szN(ish) + offs arrays + bsum
    const size_t need_full = 2 * szA + 4 * szE + 10 * (szN + 256) + 2 * 4096 + 65536;
    const bool grouped = (ws_size >= need_full);

    char* p = (char*)d_ws;
    auto alloc = [&](size_t bytes) { char* r = p; p += (bytes + 255) & ~(size_t)255; return r; };
    float* bufA    = (float*)alloc(szA);
    float* bufB    = (float*)alloc(szA);
    int*   csr_s   = (int*)alloc(szE);
    int*   csr_e   = grouped ? (int*)alloc(szE) : nullptr;
    int*   csrn_s  = grouped ? (int*)alloc(szE) : nullptr;
    int*   csrn_e  = grouped ? (int*)alloc(szE) : nullptr;
    float* nrm     = (float*)alloc(szN);
    float* nrm2    = (float*)alloc(szN);
    int*   deg     = (int*)alloc(szN);
    int*   degn    = grouped ? (int*)alloc(szN) : nullptr;
    int*   offs    = (int*)alloc(szN + 4);
    int*   pos     = (int*)alloc(szN);
    int*   offsn   = grouped ? (int*)alloc(szN + 4) : nullptr;
    int*   posn    = grouped ? (int*)alloc(szN) : nullptr;
    int*   bsum    = (int*)alloc(4096);
    int*   bsumn   = grouped ? (int*)alloc(4096) : nullptr;

    // zero degree counters (covers deg..degn incl. padding)
    if (grouped) {
        hipMemsetAsync(deg, 0, (size_t)((char*)degn - (char*)deg) + szN, stream);
    } else {
        hipMemsetAsync(deg, 0, szN, stream);
    }

    k_count2<<<2048, 256, 0, stream>>>(dst, grouped ? ndst : nullptr, deg, degn, E);
    k_norm<<<(N + 255) / 256, 256, 0, stream>>>(deg, nrm, nrm2, N);

    k_scan1<<<SCAN_B, 256, 0, stream>>>(deg, bsum, N);
    k_scan2<<<1, 512, 0, stream>>>(bsum, SCAN_B, offs + N);
    k_scan3<<<SCAN_B, 256, 0, stream>>>(deg, bsum, offs, pos, N);
    if (grouped) {
        k_scan1<<<SCAN_B, 256, 0, stream>>>(degn, bsumn, N);
        k_scan2<<<1, 512, 0, stream>>>(bsumn, SCAN_B, offsn + N);
        k_scan3<<<SCAN_B, 256, 0, stream>>>(degn, bsumn, offsn, posn, N);
    }

    k_fill2<<<2048, 256, 0, stream>>>(src, dst, pos, csr_s, csr_e, E);
    if (grouped)
        k_fill2<<<2048, 256, 0, stream>>>(nsrc, ndst, posn, csrn_s, csrn_e, E);

    const int HW_BLOCKS = (N * 32 + 255) / 256;  // one half-wave per node
    k_scale<<<(N * 32 + 255) / 256, 256, 0, stream>>>(emb, nrm, bufA, N * 32);
    k_hop<<<HW_BLOCKS, 256, 0, stream>>>(bufA, nrm2, offs, csr_s, bufB, N);
    k_hop<<<HW_BLOCKS, 256, 0, stream>>>(bufB, nrm, offs, csr_s, bufA, N);
    k_linear<<<2048, 256, 0, stream>>>(bufA, W, bia, bufB, N);

    if (grouped) {
        k_dotg<<<HW_BLOCKS, 256, 0, stream>>>(bufB, offs, csr_s, csr_e, out, N);
        k_dotg<<<HW_BLOCKS, 256, 0, stream>>>(bufB, offsn, csrn_s, csrn_e, out + E, N);
    } else {
        k_dot<<<8192, 256, 0, stream>>>(bufB, src, dst, nsrc, ndst, out, E);
    }
}

// Round 3
// 1591.686 us; speedup vs baseline: 1.2865x; 1.1886x over previous
//
#include <hip/hip_runtime.h>

#define EMB 128

// ---- bf16 helpers (RNE) --------------------------------------------------
__device__ inline unsigned short f2bf(float f) {
    union { float f; unsigned u; } v; v.f = f;
    unsigned r = v.u + 0x7FFF + ((v.u >> 16) & 1);
    return (unsigned short)(r >> 16);
}
__device__ inline float bf2f(unsigned short b) {
    union { unsigned u; float f; } v; v.u = ((unsigned)b) << 16;
    return v.f;
}

// ---- degree count (pos dst always; neg dst if degn != null) -------------
__global__ void k_count2(const int* __restrict__ dst, const int* __restrict__ ndst,
                         int* __restrict__ deg, int* __restrict__ degn, int E) {
    int i = blockIdx.x * blockDim.x + threadIdx.x;
    int stride = gridDim.x * blockDim.x;
    for (; i < E; i += stride) {
        atomicAdd(&deg[dst[i]], 1);
        if (degn) atomicAdd(&degn[ndst[i]], 1);
    }
}

// ---- norm = 1/sqrt(max(deg,1)), norm2 = norm*norm ------------------------
__global__ void k_norm(const int* __restrict__ deg, float* __restrict__ nrm,
                       float* __restrict__ nrm2, int N) {
    int i = blockIdx.x * blockDim.x + threadIdx.x;
    if (i < N) {
        float d = fmaxf((float)deg[i], 1.0f);
        float r = 1.0f / sqrtf(d);
        nrm[i] = r;
        nrm2[i] = r * r;
    }
}

// ---- 3-phase scan --------------------------------------------------------
__global__ __launch_bounds__(256) void k_scan1(const int* __restrict__ v,
                                               int* __restrict__ bsum, int n) {
    __shared__ int w4[4];
    const int t = threadIdx.x, lane = t & 63, wid = t >> 6;
    const int i = blockIdx.x * 256 + t;
    int x = (i < n) ? v[i] : 0;
    #pragma unroll
    for (int o = 32; o > 0; o >>= 1) x += __shfl_xor(x, o);
    if (lane == 0) w4[wid] = x;
    __syncthreads();
    if (t == 0) bsum[blockIdx.x] = w4[0] + w4[1] + w4[2] + w4[3];
}

__global__ __launch_bounds__(512) void k_scan2(int* __restrict__ bsum, int B,
                                               int* __restrict__ total_out) {
    __shared__ int w8[8];
    __shared__ int carry_s;
    const int t = threadIdx.x, lane = t & 63, wid = t >> 6;
    if (t == 0) carry_s = 0;
    __syncthreads();
    for (int base = 0; base < B; base += 512) {
        const int idx = base + t;
        const int v = (idx < B) ? bsum[idx] : 0;
        int s = v;
        #pragma unroll
        for (int o = 1; o < 64; o <<= 1) {
            int g = __shfl_up(s, o);
            if (lane >= o) s += g;
        }
        if (lane == 63) w8[wid] = s;
        __syncthreads();
        if (t < 8) {
            int u = w8[t];
            #pragma unroll
            for (int o = 1; o < 8; o <<= 1) {
                int g = __shfl_up(u, o);
                if (t >= o) u += g;
            }
            w8[t] = u;
        }
        __syncthreads();
        const int woff = wid ? w8[wid - 1] : 0;
        const int c = carry_s;
        if (idx < B) bsum[idx] = c + woff + s - v;
        const int tot = w8[7];
        __syncthreads();
        if (t == 0) carry_s = c + tot;
        __syncthreads();
    }
    if (t == 0 && total_out) *total_out = carry_s;
}

__global__ __launch_bounds__(256) void k_scan3(const int* __restrict__ v,
                                               const int* __restrict__ bexcl,
                                               int* __restrict__ offs,
                                               int* __restrict__ pos, int n) {
    __shared__ int w4[4];
    const int t = threadIdx.x, lane = t & 63, wid = t >> 6;
    const int i = blockIdx.x * 256 + t;
    const int x = (i < n) ? v[i] : 0;
    int s = x;
    #pragma unroll
    for (int o = 1; o < 64; o <<= 1) {
        int g = __shfl_up(s, o);
        if (lane >= o) s += g;
    }
    if (lane == 63) w4[wid] = s;
    __syncthreads();
    int woff = 0;
    for (int k = 0; k < wid; ++k) woff += w4[k];
    const int excl = bexcl[blockIdx.x] + woff + s - x;
    if (i < n) { offs[i] = excl; pos[i] = excl; }
}

// ---- counting-sort fill --------------------------------------------------
__global__ void k_fill2(const int* __restrict__ src, const int* __restrict__ dst,
                        int* __restrict__ pos, int* __restrict__ cs,
                        int* __restrict__ ce, int E) {
    int i = blockIdx.x * blockDim.x + threadIdx.x;
    int stride = gridDim.x * blockDim.x;
    for (; i < E; i += stride) {
        int p = atomicAdd(&pos[dst[i]], 1);
        cs[p] = src[i];
        if (ce) ce[p] = i;
    }
}

// ---- elementwise: o[i][*] = x[i][*] * s[i] --------------------------------
__global__ void k_scale(const float* __restrict__ x, const float* __restrict__ s,
                        float* __restrict__ o, int total4) {
    int idx = blockIdx.x * blockDim.x + threadIdx.x;
    if (idx < total4) {
        const int node = idx >> 5;
        float4 v = ((const float4*)x)[idx];
        const float f = s[node];
        float4 r; r.x = v.x * f; r.y = v.y * f; r.z = v.z * f; r.w = v.w * f;
        ((float4*)o)[idx] = r;
    }
}

// ---- one gather-sum hop (f32): half-wave per node -------------------------
__global__ __launch_bounds__(256) void k_hop(const float* __restrict__ in,
                                             const float* __restrict__ oscale,
                                             const int* __restrict__ offs,
                                             const int* __restrict__ csr,
                                             float* __restrict__ out, int N) {
    const int l = threadIdx.x & 31;
    int hw = (blockIdx.x * blockDim.x + threadIdx.x) >> 5;
    const int nhw = (gridDim.x * blockDim.x) >> 5;
    for (int i = hw; i < N; i += nhw) {
        const int jb = offs[i], je = offs[i + 1];
        float4 acc; acc.x = 0.f; acc.y = 0.f; acc.z = 0.f; acc.w = 0.f;
        int j = jb;
        for (; j + 4 <= je; j += 4) {
            const int c0 = csr[j], c1 = csr[j + 1], c2 = csr[j + 2], c3 = csr[j + 3];
            const float4 v0 = *(const float4*)&in[(size_t)c0 * EMB + 4 * l];
            const float4 v1 = *(const float4*)&in[(size_t)c1 * EMB + 4 * l];
            const float4 v2 = *(const float4*)&in[(size_t)c2 * EMB + 4 * l];
            const float4 v3 = *(const float4*)&in[(size_t)c3 * EMB + 4 * l];
            acc.x += v0.x; acc.y += v0.y; acc.z += v0.z; acc.w += v0.w;
            acc.x += v1.x; acc.y += v1.y; acc.z += v1.z; acc.w += v1.w;
            acc.x += v2.x; acc.y += v2.y; acc.z += v2.z; acc.w += v2.w;
            acc.x += v3.x; acc.y += v3.y; acc.z += v3.z; acc.w += v3.w;
        }
        for (; j < je; ++j) {
            const int c = csr[j];
            const float4 v = *(const float4*)&in[(size_t)c * EMB + 4 * l];
            acc.x += v.x; acc.y += v.y; acc.z += v.z; acc.w += v.w;
        }
        const float s = oscale[i];
        float4 o; o.x = acc.x * s; o.y = acc.y * s; o.z = acc.z * s; o.w = acc.w * s;
        *(float4*)&out[(size_t)i * EMB + 4 * l] = o;
    }
}

// ---- linear: y(bf16) = h @ W.T + bias — register-tiled GEMM ---------------
// block: 256 threads, 128 rows. per-thread 8 rows x 8 cols f32 acc.
#define LIN_RT 128
__global__ __launch_bounds__(256) void k_lin(const float* __restrict__ h,
                                             const float* __restrict__ W,
                                             const float* __restrict__ bias,
                                             unsigned short* __restrict__ y, int N) {
    __shared__ float Wl[128 * 128];      // Wl[k*128+j] = W[j*128+k]
    __shared__ float hl[LIN_RT * 129];   // hl[r*129+k], odd stride: conflict-free k-reads
    const int t = threadIdx.x;
    const int r0g = blockIdx.x * LIN_RT;
    const int nv = min(LIN_RT, N - r0g);

    {   // stage W transposed; lanes vary j -> conflict-free writes
        const int j = t & 127, k0 = (t >> 7) * 64;
        #pragma unroll
        for (int c = 0; c < 16; ++c) {
            const float4 v = *(const float4*)&W[j * 128 + k0 + 4 * c];
            Wl[(k0 + 4 * c + 0) * 128 + j] = v.x;
            Wl[(k0 + 4 * c + 1) * 128 + j] = v.y;
            Wl[(k0 + 4 * c + 2) * 128 + j] = v.z;
            Wl[(k0 + 4 * c + 3) * 128 + j] = v.w;
        }
    }
    for (int e = t; e < LIN_RT * 32; e += 256) {  // stage h (coalesced reads)
        const int r = e >> 5, q = e & 31;
        float4 v; v.x = 0.f; v.y = 0.f; v.z = 0.f; v.w = 0.f;
        if (r < nv) v = *(const float4*)&h[(size_t)(r0g + r) * EMB + 4 * q];
        hl[r * 129 + 4 * q + 0] = v.x;
        hl[r * 129 + 4 * q + 1] = v.y;
        hl[r * 129 + 4 * q + 2] = v.z;
        hl[r * 129 + 4 * q + 3] = v.w;
    }
    __syncthreads();

    const int tc = t & 15, tr = t >> 4;
    const int rb = tr * 8;
    const int j0 = 4 * tc, j1 = 64 + 4 * tc;
    float acc[8][8];
    #pragma unroll
    for (int a = 0; a < 8; ++a)
        #pragma unroll
        for (int b = 0; b < 8; ++b) acc[a][b] = 0.f;

    #pragma unroll 2
    for (int k = 0; k < 128; ++k) {
        const float4 w0 = *(const float4*)&Wl[k * 128 + j0];
        const float4 w1 = *(const float4*)&Wl[k * 128 + j1];
        float hreg[8];
        #pragma unroll
        for (int a = 0; a < 8; ++a) hreg[a] = hl[(rb + a) * 129 + k];
        #pragma unroll
        for (int a = 0; a < 8; ++a) {
            acc[a][0] += hreg[a] * w0.x; acc[a][1] += hreg[a] * w0.y;
            acc[a][2] += hreg[a] * w0.z; acc[a][3] += hreg[a] * w0.w;
            acc[a][4] += hreg[a] * w1.x; acc[a][5] += hreg[a] * w1.y;
            acc[a][6] += hreg[a] * w1.z; acc[a][7] += hreg[a] * w1.w;
        }
    }

    const float4 b0 = *(const float4*)&bias[j0];
    const float4 b1 = *(const float4*)&bias[j1];
    #pragma unroll
    for (int a = 0; a < 8; ++a) {
        const int r = rb + a;
        if (r < nv) {
            ushort4 p0, p1;
            p0.x = f2bf(acc[a][0] + b0.x); p0.y = f2bf(acc[a][1] + b0.y);
            p0.z = f2bf(acc[a][2] + b0.z); p0.w = f2bf(acc[a][3] + b0.w);
            p1.x = f2bf(acc[a][4] + b1.x); p1.y = f2bf(acc[a][5] + b1.y);
            p1.z = f2bf(acc[a][6] + b1.z); p1.w = f2bf(acc[a][7] + b1.w);
            *(ushort4*)&y[(size_t)(r0g + r) * EMB + j0] = p0;
            *(ushort4*)&y[(size_t)(r0g + r) * EMB + j1] = p1;
        }
    }
}

// ---- grouped edge dots on bf16 y: half-wave per node ----------------------
__global__ __launch_bounds__(256) void k_dotg(const unsigned short* __restrict__ y,
                                              const int* __restrict__ offs,
                                              const int* __restrict__ cs,
                                              const int* __restrict__ ce,
                                              float* __restrict__ out, int N) {
    const int l = threadIdx.x & 31;
    int hw = (blockIdx.x * blockDim.x + threadIdx.x) >> 5;
    const int nhw = (gridDim.x * blockDim.x) >> 5;
    for (int i = hw; i < N; i += nhw) {
        const int jb = offs[i], je = offs[i + 1];
        if (jb == je) continue;
        const ushort4 dv = *(const ushort4*)&y[(size_t)i * EMB + 4 * l];
        const float dx = bf2f(dv.x), dy = bf2f(dv.y), dz = bf2f(dv.z), dw = bf2f(dv.w);
        int j = jb;
        for (; j + 2 <= je; j += 2) {
            const int c0 = cs[j], c1 = cs[j + 1];
            const int e0 = ce[j], e1 = ce[j + 1];
            const ushort4 a0 = *(const ushort4*)&y[(size_t)c0 * EMB + 4 * l];
            const ushort4 a1 = *(const ushort4*)&y[(size_t)c1 * EMB + 4 * l];
            float v0 = bf2f(a0.x) * dx + bf2f(a0.y) * dy + bf2f(a0.z) * dz + bf2f(a0.w) * dw;
            float v1 = bf2f(a1.x) * dx + bf2f(a1.y) * dy + bf2f(a1.z) * dz + bf2f(a1.w) * dw;
            v0 += __shfl_xor(v0, 16); v1 += __shfl_xor(v1, 16);
            v0 += __shfl_xor(v0, 8);  v1 += __shfl_xor(v1, 8);
            v0 += __shfl_xor(v0, 4);  v1 += __shfl_xor(v1, 4);
            v0 += __shfl_xor(v0, 2);  v1 += __shfl_xor(v1, 2);
            v0 += __shfl_xor(v0, 1);  v1 += __shfl_xor(v1, 1);
            if (l == 0) { out[e0] = v0; out[e1] = v1; }
        }
        if (j < je) {
            const int c0 = cs[j], e0 = ce[j];
            const ushort4 a0 = *(const ushort4*)&y[(size_t)c0 * EMB + 4 * l];
            float v0 = bf2f(a0.x) * dx + bf2f(a0.y) * dy + bf2f(a0.z) * dz + bf2f(a0.w) * dw;
            v0 += __shfl_xor(v0, 16); v0 += __shfl_xor(v0, 8);
            v0 += __shfl_xor(v0, 4);  v0 += __shfl_xor(v0, 2);
            v0 += __shfl_xor(v0, 1);
            if (l == 0) out[e0] = v0;
        }
    }
}

// ---- fallback ungrouped dots (bf16 y) ------------------------------------
__global__ __launch_bounds__(256) void k_dot(const unsigned short* __restrict__ y,
                                             const int* __restrict__ src,
                                             const int* __restrict__ dst,
                                             const int* __restrict__ nsrc,
                                             const int* __restrict__ ndst,
                                             float* __restrict__ out, int E) {
    const int lane = threadIdx.x & 63;
    const int sub = lane >> 5;
    const int l = lane & 31;
    int w = blockIdx.x * (blockDim.x >> 6) + (threadIdx.x >> 6);
    const int nw = gridDim.x * (blockDim.x >> 6);
    for (int p = w; p < E; p += nw) {
        const int e = 2 * p + sub;
        int s, d;
        if (e < E) { s = src[e]; d = dst[e]; }
        else       { s = nsrc[e - E]; d = ndst[e - E]; }
        const ushort4 a = *(const ushort4*)&y[(size_t)s * EMB + 4 * l];
        const ushort4 c = *(const ushort4*)&y[(size_t)d * EMB + 4 * l];
        float v = bf2f(a.x) * bf2f(c.x) + bf2f(a.y) * bf2f(c.y) +
                  bf2f(a.z) * bf2f(c.z) + bf2f(a.w) * bf2f(c.w);
        v += __shfl_xor(v, 16); v += __shfl_xor(v, 8); v += __shfl_xor(v, 4);
        v += __shfl_xor(v, 2);  v += __shfl_xor(v, 1);
        if (l == 0) out[e] = v;
    }
}

extern "C" void kernel_launch(void* const* d_in, const int* in_sizes, int n_in,
                              void* d_out, int out_size, void* d_ws, size_t ws_size,
                              hipStream_t stream) {
    const float* emb = (const float*)d_in[0];
    const float* W   = (const float*)d_in[1];
    const float* bia = (const float*)d_in[2];
    const int* src   = (const int*)d_in[3];
    const int* dst   = (const int*)d_in[4];
    const int* nsrc  = (const int*)d_in[5];
    const int* ndst  = (const int*)d_in[6];
    const int N = in_sizes[0] / EMB;
    const int E = in_sizes[3];
    float* out = (float*)d_out;

    const size_t szA = (size_t)N * EMB * sizeof(float);
    const size_t szN = (size_t)N * sizeof(int);
    const size_t szE = (size_t)E * sizeof(int);
    const int SCAN_B = (N + 255) / 256;

    const size_t need_full = 2 * szA + 4 * szE + 10 * (szN + 256) + 2 * 4096 + 65536;
    const bool grouped = (ws_size >= need_full);

    char* p = (char*)d_ws;
    auto alloc = [&](size_t bytes) { char* r = p; p += (bytes + 255) & ~(size_t)255; return r; };
    float* bufA    = (float*)alloc(szA);
    float* bufB    = (float*)alloc(szA);   // H1, then y(bf16) lives here
    int*   csr_s   = (int*)alloc(szE);
    int*   csr_e   = grouped ? (int*)alloc(szE) : nullptr;
    int*   csrn_s  = grouped ? (int*)alloc(szE) : nullptr;
    int*   csrn_e  = grouped ? (int*)alloc(szE) : nullptr;
    float* nrm     = (float*)alloc(szN);
    float* nrm2    = (float*)alloc(szN);
    int*   deg     = (int*)alloc(szN);
    int*   degn    = grouped ? (int*)alloc(szN) : nullptr;
    int*   offs    = (int*)alloc(szN + 4);
    int*   pos     = (int*)alloc(szN);
    int*   offsn   = grouped ? (int*)alloc(szN + 4) : nullptr;
    int*   posn    = grouped ? (int*)alloc(szN) : nullptr;
    int*   bsum    = (int*)alloc(4096);
    int*   bsumn   = grouped ? (int*)alloc(4096) : nullptr;
    unsigned short* ybf = (unsigned short*)bufB;  // overlays dead H1

    if (grouped) {
        hipMemsetAsync(deg, 0, (size_t)((char*)degn - (char*)deg) + szN, stream);
    } else {
        hipMemsetAsync(deg, 0, szN, stream);
    }

    k_count2<<<2048, 256, 0, stream>>>(dst, grouped ? ndst : nullptr, deg, degn, E);
    k_norm<<<(N + 255) / 256, 256, 0, stream>>>(deg, nrm, nrm2, N);

    k_scan1<<<SCAN_B, 256, 0, stream>>>(deg, bsum, N);
    k_scan2<<<1, 512, 0, stream>>>(bsum, SCAN_B, offs + N);
    k_scan3<<<SCAN_B, 256, 0, stream>>>(deg, bsum, offs, pos, N);
    if (grouped) {
        k_scan1<<<SCAN_B, 256, 0, stream>>>(degn, bsumn, N);
        k_scan2<<<1, 512, 0, stream>>>(bsumn, SCAN_B, offsn + N);
        k_scan3<<<SCAN_B, 256, 0, stream>>>(degn, bsumn, offsn, posn, N);
    }

    k_fill2<<<2048, 256, 0, stream>>>(src, dst, pos, csr_s, csr_e, E);
    if (grouped)
        k_fill2<<<2048, 256, 0, stream>>>(nsrc, ndst, posn, csrn_s, csrn_e, E);

    const int HW_BLOCKS = (N * 32 + 255) / 256;
    k_scale<<<(N * 32 + 255) / 256, 256, 0, stream>>>(emb, nrm, bufA, N * 32);
    k_hop<<<HW_BLOCKS, 256, 0, stream>>>(bufA, nrm2, offs, csr_s, bufB, N);   // H1 -> bufB
    k_hop<<<HW_BLOCKS, 256, 0, stream>>>(bufB, nrm, offs, csr_s, bufA, N);    // H2 -> bufA
    k_lin<<<(N + LIN_RT - 1) / LIN_RT, 256, 0, stream>>>(bufA, W, bia, ybf, N);

    if (grouped) {
        k_dotg<<<HW_BLOCKS, 256, 0, stream>>>(ybf, offs, csr_s, csr_e, out, N);
        k_dotg<<<HW_BLOCKS, 256, 0, stream>>>(ybf, offsn, csrn_s, csrn_e, out + E, N);
    } else {
        k_dot<<<8192, 256, 0, stream>>>(ybf, src, dst, nsrc, ndst, out, E);
    }
}